// Round 8
// baseline (88.986 us; speedup 1.0000x reference)
//
#include <hip/hip_runtime.h>

#define BINW 128          // dsts per bin
#define CAP  2560         // max edges per bin (mean 2048, sigma ~45 -> +11 sigma)
#define EPB  2048         // edges per bin-path block (8 per thread)
#define MAXBINS 512

union SMem1 {
    float ws[128 * 64];                        // proj path: 32 KB
    struct { int cursor[MAXBINS], gpos[MAXBINS]; } b;  // bin path: 4 KB
};

union SMem2 {
    struct {                                   // bincsr path: ~11.8 KB
        unsigned data[CAP];
        int hist[BINW], lstart[BINW], cursor[BINW];
    } c;
    int dummy;                                 // node path: unused
};

__device__ __forceinline__ unsigned pack_bf16x2(float x, float y) {
    unsigned ux = __float_as_uint(x); ux += 0x7fffu + ((ux >> 16) & 1);
    unsigned uy = __float_as_uint(y); uy += 0x7fffu + ((uy >> 16) & 1);
    return (ux >> 16) | (uy & 0xffff0000u);
}

// Stage 1: blocks [0, bin_blocks) bin edges (runs FIRST so the LDS-atomic path
// overlaps the proj GEMM); blocks [bin_blocks, ...) do hw = h @ Ww + bw and
// also emit a bf16 copy of hw for the gather kernel.
__global__ __launch_bounds__(256) void k_s1(
    const float* __restrict__ h, const float* __restrict__ Ww,
    const float* __restrict__ bw,
    const int* __restrict__ src, const int* __restrict__ dst,
    float* __restrict__ hw, unsigned short* __restrict__ hw16,
    int* __restrict__ bin_cnt, unsigned* __restrict__ binned,
    int n_nodes, int n_edges, int nbins, int bin_blocks)
{
    __shared__ SMem1 u;
    const int t = threadIdx.x;

    if ((int)blockIdx.x < bin_blocks) {
        // ------- bin: rank within (block,bin), reserve, direct scatter -------
        const int e0 = blockIdx.x * EPB;
        for (int i = t; i < nbins; i += 256) u.b.cursor[i] = 0;
        __syncthreads();

        unsigned myw[8]; int myr[8];
#pragma unroll
        for (int k = 0; k < 8; ++k) {
            int e = e0 + k * 256 + t;
            myw[k] = 0xffffffffu;
            if (e < n_edges) {
                int d = dst[e], s = src[e];
                int b = d >> 7;
                myw[k] = ((unsigned)b << 23) | ((unsigned)s << 7) | (unsigned)(d & 127);
                myr[k] = atomicAdd(&u.b.cursor[b], 1);
            }
        }
        __syncthreads();
        for (int i = t; i < nbins; i += 256) {
            int c = u.b.cursor[i];
            u.b.gpos[i] = c ? atomicAdd(&bin_cnt[i * 16], c) : 0;
        }
        __syncthreads();
#pragma unroll
        for (int k = 0; k < 8; ++k) {
            unsigned w = myw[k];
            if (w != 0xffffffffu) {
                int b = w >> 23;
                binned[b * CAP + u.b.gpos[b] + myr[k]] = w & 0x7fffffu;
            }
        }
    } else {
        // ---------------- proj: hw = h @ Ww + bw ----------------
#pragma unroll
        for (int i = 0; i < 32; ++i)
            u.ws[i * 256 + t] = Ww[i * 256 + t];
        __syncthreads();

        const int lane = t & 63;
        const int wid  = t >> 6;
        const int cp   = lane & 31;
        const int rsub = lane >> 5;
        const int row0 = (((int)blockIdx.x - bin_blocks) * 4 + wid) * 8 + rsub * 4;
        if (row0 >= n_nodes) return;

        float acc[4][2] = {{0.f,0.f},{0.f,0.f},{0.f,0.f},{0.f,0.f}};
        const float* hrow = h + (size_t)row0 * 128;

        for (int k = 0; k < 128; k += 4) {
            float ha[4][4];
#pragma unroll
            for (int r = 0; r < 4; ++r)
                *(float4*)ha[r] = *(const float4*)(hrow + r * 128 + k);
#pragma unroll
            for (int kk = 0; kk < 4; ++kk) {
                float2 w2 = *(const float2*)(&u.ws[(k + kk) * 64 + cp * 2]);
#pragma unroll
                for (int r = 0; r < 4; ++r) {
                    acc[r][0] = __fmaf_rn(ha[r][kk], w2.x, acc[r][0]);
                    acc[r][1] = __fmaf_rn(ha[r][kk], w2.y, acc[r][1]);
                }
            }
        }
        const float b0 = bw[cp * 2], b1 = bw[cp * 2 + 1];
#pragma unroll
        for (int r = 0; r < 4; ++r) {
            float2 o;
            o.x = acc[r][0] + b0;
            o.y = acc[r][1] + b1;
            const size_t idx = (size_t)(row0 + r) * 64 + cp * 2;
            *(float2*)(hw + idx) = o;
            *(unsigned*)(hw16 + idx) = pack_bf16x2(o.x, o.y);
        }
    }
}

// Stage 2: blocks [0, nbins) build per-bin CSR; the rest compute per-(node,head)
// attention dots asrc/adst from the f32 hw.
__global__ __launch_bounds__(256) void k_s2(
    const int* __restrict__ bin_cnt, unsigned* __restrict__ binned,
    int* __restrict__ row_start, int* __restrict__ row_cnt,
    const float* __restrict__ hw, const float* __restrict__ Wa,
    const float* __restrict__ ba_p,
    float* __restrict__ asrc, float* __restrict__ adst,
    int n_nodes, int nbins, int n4)
{
    __shared__ SMem2 u;
    const int t = threadIdx.x;

    if ((int)blockIdx.x < nbins) {
        const int b = blockIdx.x;
        const int cnt = min(bin_cnt[b * 16], CAP);
        const int base = b * CAP;

        if (t < BINW) u.c.hist[t] = 0;
        __syncthreads();
        for (int i = t; i < cnt; i += 256) {
            unsigned w = binned[base + i];
            u.c.data[i] = w;
            atomicAdd(&u.c.hist[w & 127], 1);
        }
        __syncthreads();
        if (t < 64) {
            int carry = 0;
#pragma unroll
            for (int half = 0; half < 2; ++half) {
                int i = half * 64 + t;
                int v = u.c.hist[i];
                int x = v;
#pragma unroll
                for (int off = 1; off < 64; off <<= 1) {
                    int n_ = __shfl_up(x, off);
                    if (t >= off) x += n_;
                }
                u.c.lstart[i] = carry + x - v;
                u.c.cursor[i] = carry + x - v;
                carry += __shfl(x, 63);
            }
        }
        __syncthreads();
        for (int i = t; i < cnt; i += 256) {
            unsigned w = u.c.data[i];
            int pos = atomicAdd(&u.c.cursor[w & 127], 1);
            binned[base + pos] = w;
        }
        const int d0 = b * BINW;
        if (t < BINW && d0 + t < n_nodes) {
            row_start[d0 + t] = base + u.c.lstart[t];
            row_cnt[d0 + t] = u.c.hist[t];
        }
    } else {
        int i = ((int)blockIdx.x - nbins) * 256 + t;
        if (i >= n4) return;
        const float* hp = hw + (size_t)i * 16;
        float as = 0.f, ad = 0.f;
#pragma unroll
        for (int j = 0; j < 16; ++j) {
            float v = hp[j];
            as = __fmaf_rn(v, Wa[j], as);
            ad = __fmaf_rn(v, Wa[16 + j], ad);
        }
        asrc[i] = as;
        adst[i] = ad + *ba_p;
    }
}

// One wave per dst node; lane = output col. Head-dedup exp via shfl; hw in bf16.
__global__ __launch_bounds__(256) void k_gather(
    const unsigned* __restrict__ binned, const int* __restrict__ row_start,
    const int* __restrict__ row_cnt,
    const float* __restrict__ asrc, const float* __restrict__ adst,
    const unsigned short* __restrict__ hw16, float* __restrict__ out, int n_nodes)
{
    int d = blockIdx.x * 4 + (threadIdx.x >> 6);
    if (d >= n_nodes) return;
    const int lane = threadIdx.x & 63;
    const int head = lane >> 4;
    const int eloc = lane & 7;
    const int start = row_start[d];
    const int cnt = row_cnt[d];
    if (cnt <= 0) {
        out[(size_t)d * 64 + lane] = 0.f;
        return;
    }
    const int end = start + cnt;
    const float ad = adst[(unsigned)(d * 4 + head)];
    float acc = 0.f, den = 0.f;

    for (int i = start; i < end; i += 8) {
        int myi = i + eloc;
        int ld = (myi < end) ? myi : start;
        unsigned w = binned[(unsigned)ld];
        int s_p = (int)(w >> 7);
        float a = asrc[(unsigned)(s_p * 4 + head)] + ad;
        a = fmaxf(a, 0.01f * a);
        float ea = __expf(a);
        ea = (myi < end) ? ea : 0.f;
#pragma unroll
        for (int k = 0; k < 8; ++k) {
            int   s_k  = __shfl(s_p, k);
            float ea_k = __shfl(ea, k | (head << 4));
            den += ea_k;
            float hv = __uint_as_float((unsigned)hw16[(unsigned)(s_k * 64 + lane)] << 16);
            acc = __fmaf_rn(ea_k, hv, acc);
        }
    }
    out[(size_t)d * 64 + lane] = acc / den;
}

extern "C" void kernel_launch(void* const* d_in, const int* in_sizes, int n_in,
                              void* d_out, int out_size, void* d_ws, size_t ws_size,
                              hipStream_t stream)
{
    const float* h  = (const float*)d_in[0];
    const float* Ww = (const float*)d_in[1];
    const float* bw = (const float*)d_in[2];
    const float* Wa = (const float*)d_in[3];
    const float* ba = (const float*)d_in[4];
    const int* src  = (const int*)d_in[5];
    const int* dst  = (const int*)d_in[6];

    const int n_nodes = in_sizes[0] / 128;
    const int n_edges = in_sizes[5];
    const int nbins = (n_nodes + BINW - 1) / BINW;   // 391

    // Workspace (4B words):
    // hw[N*64] f32 | hw16[N*64] bf16 | asrc[N*4] | adst[N*4] |
    // row_start[N] | row_cnt[N] | bin_cnt[nbins*16] | binned[nbins*CAP]
    float* hw            = (float*)d_ws;
    unsigned short* hw16 = (unsigned short*)(hw + (size_t)n_nodes * 64);
    float* asrc          = (float*)(hw16 + (size_t)n_nodes * 64);
    float* adst          = asrc + (size_t)n_nodes * 4;
    int* row_start       = (int*)(adst + (size_t)n_nodes * 4);
    int* row_cnt         = row_start + n_nodes;
    int* bin_cnt         = row_cnt + n_nodes;
    unsigned* binned     = (unsigned*)(bin_cnt + (size_t)nbins * 16);

    float* out = (float*)d_out;

    hipMemsetAsync(bin_cnt, 0, (size_t)nbins * 16 * sizeof(int), stream);

    const int bin_blocks  = (n_edges + EPB - 1) / EPB;      // 391
    const int proj_blocks = (n_nodes + 31) / 32;            // 1563
    k_s1<<<bin_blocks + proj_blocks, 256, 0, stream>>>(
        h, Ww, bw, src, dst, hw, hw16, bin_cnt, binned,
        n_nodes, n_edges, nbins, bin_blocks);

    const int n4 = n_nodes * 4;
    const int node_blocks = (n4 + 255) / 256;               // 782
    k_s2<<<nbins + node_blocks, 256, 0, stream>>>(
        bin_cnt, binned, row_start, row_cnt, hw, Wa, ba, asrc, adst, n_nodes, nbins, n4);

    k_gather<<<(n_nodes + 3) / 4, 256, 0, stream>>>(
        binned, row_start, row_cnt, asrc, adst, hw16, out, n_nodes);
}

// Round 9
// 86.182 us; speedup vs baseline: 1.0325x; 1.0325x over previous
//
#include <hip/hip_runtime.h>

#define BINW 128          // dsts per bin
#define CAP  2560         // max edges per bin (mean 2048, sigma ~45 -> +11 sigma)
#define EPB  2048         // edges per bin block (8 per thread)
#define MAXBINS 512

__device__ __forceinline__ unsigned pack_bf16x2(float x, float y) {
    unsigned ux = __float_as_uint(x); ux += 0x7fffu + ((ux >> 16) & 1);
    unsigned uy = __float_as_uint(y); uy += 0x7fffu + ((uy >> 16) & 1);
    return (ux >> 16) | (uy & 0xffff0000u);
}

// Bin edges by dst>>7: rank within (block,bin) via LDS cursor, reserve global
// segment, direct scatter. 4KB LDS -> 8 blocks/CU.
__global__ __launch_bounds__(256) void k_bin(
    const int* __restrict__ src, const int* __restrict__ dst,
    int* __restrict__ bin_cnt, unsigned* __restrict__ binned,
    int n_edges, int nbins)
{
    __shared__ int cursor[MAXBINS], gpos[MAXBINS];
    const int t = threadIdx.x;
    const int e0 = blockIdx.x * EPB;

    for (int i = t; i < nbins; i += 256) cursor[i] = 0;
    __syncthreads();

    unsigned myw[8]; int myr[8];
#pragma unroll
    for (int k = 0; k < 8; ++k) {
        int e = e0 + k * 256 + t;
        myw[k] = 0xffffffffu;
        if (e < n_edges) {
            int d = dst[e], s = src[e];
            int b = d >> 7;
            myw[k] = ((unsigned)b << 23) | ((unsigned)s << 7) | (unsigned)(d & 127);
            myr[k] = atomicAdd(&cursor[b], 1);
        }
    }
    __syncthreads();
    for (int i = t; i < nbins; i += 256) {
        int c = cursor[i];
        gpos[i] = c ? atomicAdd(&bin_cnt[i * 16], c) : 0;
    }
    __syncthreads();
#pragma unroll
    for (int k = 0; k < 8; ++k) {
        unsigned w = myw[k];
        if (w != 0xffffffffu) {
            int b = w >> 23;
            binned[b * CAP + gpos[b] + myr[k]] = w & 0x7fffffu;
        }
    }
}

// hw = h @ Ww + bw  (N x 128)@(128 x 64). Wave = 16 rows x 64 cols; each thread
// 4 rows x 4 cols (b128 LDS reads, half the waves/instrs of the 2-col layout).
__global__ __launch_bounds__(256) void k_proj(
    const float* __restrict__ h, const float* __restrict__ Ww,
    const float* __restrict__ bw, float* __restrict__ hw,
    unsigned short* __restrict__ hw16, int n_nodes)
{
    __shared__ float ws[128 * 64];
#pragma unroll
    for (int i = 0; i < 8; ++i)
        ((float4*)ws)[i * 256 + threadIdx.x] = ((const float4*)Ww)[i * 256 + threadIdx.x];
    __syncthreads();

    const int lane = threadIdx.x & 63;
    const int wid  = threadIdx.x >> 6;
    const int cg   = lane & 15;     // cols 4cg .. 4cg+3
    const int rsub = lane >> 4;     // 0..3
    const int row0 = (blockIdx.x * 4 + wid) * 16 + rsub * 4;
    if (row0 >= n_nodes) return;

    float acc[4][4];
#pragma unroll
    for (int r = 0; r < 4; ++r)
#pragma unroll
        for (int c = 0; c < 4; ++c) acc[r][c] = 0.f;

    const float* hrow = h + (size_t)row0 * 128;

    for (int k = 0; k < 128; k += 4) {
        float ha[4][4];
#pragma unroll
        for (int r = 0; r < 4; ++r)
            *(float4*)ha[r] = *(const float4*)(hrow + r * 128 + k);
#pragma unroll
        for (int kk = 0; kk < 4; ++kk) {
            float4 w4 = *(const float4*)(&ws[(k + kk) * 64 + cg * 4]);
#pragma unroll
            for (int r = 0; r < 4; ++r) {
                acc[r][0] = __fmaf_rn(ha[r][kk], w4.x, acc[r][0]);
                acc[r][1] = __fmaf_rn(ha[r][kk], w4.y, acc[r][1]);
                acc[r][2] = __fmaf_rn(ha[r][kk], w4.z, acc[r][2]);
                acc[r][3] = __fmaf_rn(ha[r][kk], w4.w, acc[r][3]);
            }
        }
    }
    const float4 b4 = *(const float4*)(bw + cg * 4);
#pragma unroll
    for (int r = 0; r < 4; ++r) {
        float4 o;
        o.x = acc[r][0] + b4.x;
        o.y = acc[r][1] + b4.y;
        o.z = acc[r][2] + b4.z;
        o.w = acc[r][3] + b4.w;
        const size_t idx = (size_t)(row0 + r) * 64 + cg * 4;
        *(float4*)(hw + idx) = o;
        uint2 p;
        p.x = pack_bf16x2(o.x, o.y);
        p.y = pack_bf16x2(o.z, o.w);
        *(uint2*)(hw16 + idx) = p;
    }
}

union SMem2 {
    struct {                                   // bincsr path: ~11.8 KB
        unsigned data[CAP];
        int hist[BINW], lstart[BINW], cursor[BINW];
    } c;
    int dummy;                                 // node path: unused
};

// Blocks [0, nbins): per-bin CSR build; rest: per-(node,head) attention dots.
__global__ __launch_bounds__(256) void k_s2(
    const int* __restrict__ bin_cnt, unsigned* __restrict__ binned,
    int* __restrict__ row_start, int* __restrict__ row_cnt,
    const float* __restrict__ hw, const float* __restrict__ Wa,
    const float* __restrict__ ba_p,
    float* __restrict__ asrc, float* __restrict__ adst,
    int n_nodes, int nbins, int n4)
{
    __shared__ SMem2 u;
    const int t = threadIdx.x;

    if ((int)blockIdx.x < nbins) {
        const int b = blockIdx.x;
        const int cnt = min(bin_cnt[b * 16], CAP);
        const int base = b * CAP;

        if (t < BINW) u.c.hist[t] = 0;
        __syncthreads();
        for (int i = t; i < cnt; i += 256) {
            unsigned w = binned[base + i];
            u.c.data[i] = w;
            atomicAdd(&u.c.hist[w & 127], 1);
        }
        __syncthreads();
        if (t < 64) {
            int carry = 0;
#pragma unroll
            for (int half = 0; half < 2; ++half) {
                int i = half * 64 + t;
                int v = u.c.hist[i];
                int x = v;
#pragma unroll
                for (int off = 1; off < 64; off <<= 1) {
                    int n_ = __shfl_up(x, off);
                    if (t >= off) x += n_;
                }
                u.c.lstart[i] = carry + x - v;
                u.c.cursor[i] = carry + x - v;
                carry += __shfl(x, 63);
            }
        }
        __syncthreads();
        for (int i = t; i < cnt; i += 256) {
            unsigned w = u.c.data[i];
            int pos = atomicAdd(&u.c.cursor[w & 127], 1);
            binned[base + pos] = w;
        }
        const int d0 = b * BINW;
        if (t < BINW && d0 + t < n_nodes) {
            row_start[d0 + t] = base + u.c.lstart[t];
            row_cnt[d0 + t] = u.c.hist[t];
        }
    } else {
        int i = ((int)blockIdx.x - nbins) * 256 + t;
        if (i >= n4) return;
        const float* hp = hw + (size_t)i * 16;
        float as = 0.f, ad = 0.f;
#pragma unroll
        for (int j = 0; j < 16; ++j) {
            float v = hp[j];
            as = __fmaf_rn(v, Wa[j], as);
            ad = __fmaf_rn(v, Wa[16 + j], ad);
        }
        asrc[i] = as;
        adst[i] = ad + *ba_p;
    }
}

// One wave per dst node; lane = output col. Head-dedup exp via shfl; hw in bf16.
__global__ __launch_bounds__(256) void k_gather(
    const unsigned* __restrict__ binned, const int* __restrict__ row_start,
    const int* __restrict__ row_cnt,
    const float* __restrict__ asrc, const float* __restrict__ adst,
    const unsigned short* __restrict__ hw16, float* __restrict__ out, int n_nodes)
{
    int d = blockIdx.x * 4 + (threadIdx.x >> 6);
    if (d >= n_nodes) return;
    const int lane = threadIdx.x & 63;
    const int head = lane >> 4;
    const int eloc = lane & 7;
    const int start = row_start[d];
    const int cnt = row_cnt[d];
    if (cnt <= 0) {
        out[(size_t)d * 64 + lane] = 0.f;
        return;
    }
    const int end = start + cnt;
    const float ad = adst[(unsigned)(d * 4 + head)];
    float acc = 0.f, den = 0.f;

    for (int i = start; i < end; i += 8) {
        int myi = i + eloc;
        int ld = (myi < end) ? myi : start;
        unsigned w = binned[(unsigned)ld];
        int s_p = (int)(w >> 7);
        float a = asrc[(unsigned)(s_p * 4 + head)] + ad;
        a = fmaxf(a, 0.01f * a);
        float ea = __expf(a);
        ea = (myi < end) ? ea : 0.f;
#pragma unroll
        for (int k = 0; k < 8; ++k) {
            int   s_k  = __shfl(s_p, k);
            float ea_k = __shfl(ea, k | (head << 4));
            den += ea_k;
            float hv = __uint_as_float((unsigned)hw16[(unsigned)(s_k * 64 + lane)] << 16);
            acc = __fmaf_rn(ea_k, hv, acc);
        }
    }
    out[(size_t)d * 64 + lane] = acc / den;
}

extern "C" void kernel_launch(void* const* d_in, const int* in_sizes, int n_in,
                              void* d_out, int out_size, void* d_ws, size_t ws_size,
                              hipStream_t stream)
{
    const float* h  = (const float*)d_in[0];
    const float* Ww = (const float*)d_in[1];
    const float* bw = (const float*)d_in[2];
    const float* Wa = (const float*)d_in[3];
    const float* ba = (const float*)d_in[4];
    const int* src  = (const int*)d_in[5];
    const int* dst  = (const int*)d_in[6];

    const int n_nodes = in_sizes[0] / 128;
    const int n_edges = in_sizes[5];
    const int nbins = (n_nodes + BINW - 1) / BINW;   // 391

    // Workspace (4B words):
    // hw[N*64] f32 | hw16[N*64] bf16 | asrc[N*4] | adst[N*4] |
    // row_start[N] | row_cnt[N] | bin_cnt[nbins*16] | binned[nbins*CAP]
    float* hw            = (float*)d_ws;
    unsigned short* hw16 = (unsigned short*)(hw + (size_t)n_nodes * 64);
    float* asrc          = (float*)(hw16 + (size_t)n_nodes * 64);
    float* adst          = asrc + (size_t)n_nodes * 4;
    int* row_start       = (int*)(adst + (size_t)n_nodes * 4);
    int* row_cnt         = row_start + n_nodes;
    int* bin_cnt         = row_cnt + n_nodes;
    unsigned* binned     = (unsigned*)(bin_cnt + (size_t)nbins * 16);

    float* out = (float*)d_out;

    hipMemsetAsync(bin_cnt, 0, (size_t)nbins * 16 * sizeof(int), stream);

    const int bin_blocks = (n_edges + EPB - 1) / EPB;       // 391
    k_bin<<<bin_blocks, 256, 0, stream>>>(src, dst, bin_cnt, binned, n_edges, nbins);

    const int proj_blocks = (n_nodes + 63) / 64;            // 782
    k_proj<<<proj_blocks, 256, 0, stream>>>(h, Ww, bw, hw, hw16, n_nodes);

    const int n4 = n_nodes * 4;
    const int node_blocks = (n4 + 255) / 256;               // 782
    k_s2<<<nbins + node_blocks, 256, 0, stream>>>(
        bin_cnt, binned, row_start, row_cnt, hw, Wa, ba, asrc, adst, n_nodes, nbins, n4);

    k_gather<<<(n_nodes + 3) / 4, 256, 0, stream>>>(
        binned, row_start, row_cnt, asrc, adst, hw16, out, n_nodes);
}

// Round 10
// 85.704 us; speedup vs baseline: 1.0383x; 1.0056x over previous
//
#include <hip/hip_runtime.h>

#define BINW 128          // dsts per bin
#define CAP  2560         // max edges per bin (mean 2048, sigma ~45 -> +11 sigma)
#define EPB  2048         // edges per bin block (8 per thread)
#define MAXBINS 512

__device__ __forceinline__ unsigned pack_bf16x2(float x, float y) {
    unsigned ux = __float_as_uint(x); ux += 0x7fffu + ((ux >> 16) & 1);
    unsigned uy = __float_as_uint(y); uy += 0x7fffu + ((uy >> 16) & 1);
    return (ux >> 16) | (uy & 0xffff0000u);
}

// Bin edges by dst>>7: rank within (block,bin) via LDS cursor, reserve global
// segment, direct scatter. 4KB LDS -> high occupancy.
__global__ __launch_bounds__(256) void k_bin(
    const int* __restrict__ src, const int* __restrict__ dst,
    int* __restrict__ bin_cnt, unsigned* __restrict__ binned,
    int n_edges, int nbins)
{
    __shared__ int cursor[MAXBINS], gpos[MAXBINS];
    const int t = threadIdx.x;
    const int e0 = blockIdx.x * EPB;

    for (int i = t; i < nbins; i += 256) cursor[i] = 0;
    __syncthreads();

    unsigned myw[8]; int myr[8];
#pragma unroll
    for (int k = 0; k < 8; ++k) {
        int e = e0 + k * 256 + t;
        myw[k] = 0xffffffffu;
        if (e < n_edges) {
            int d = dst[e], s = src[e];
            int b = d >> 7;
            myw[k] = ((unsigned)b << 23) | ((unsigned)s << 7) | (unsigned)(d & 127);
            myr[k] = atomicAdd(&cursor[b], 1);
        }
    }
    __syncthreads();
    for (int i = t; i < nbins; i += 256) {
        int c = cursor[i];
        gpos[i] = c ? atomicAdd(&bin_cnt[i * 16], c) : 0;
    }
    __syncthreads();
#pragma unroll
    for (int k = 0; k < 8; ++k) {
        unsigned w = myw[k];
        if (w != 0xffffffffu) {
            int b = w >> 23;
            binned[b * CAP + gpos[b] + myr[k]] = w & 0x7fffffu;
        }
    }
}

// hw16 = bf16(h @ Ww + bw). Wave = 16 rows x 64 cols; thread = 4 rows x 4 cols.
// Epilogue: per-(node,head) attention dots via 4-lane shfl_xor reduce
// (head's 16 cols live in 4 lanes), written as asrc / adst(+ba).
__global__ __launch_bounds__(256, 2) void k_proj(
    const float* __restrict__ h, const float* __restrict__ Ww,
    const float* __restrict__ bw, const float* __restrict__ Wa,
    const float* __restrict__ ba_p,
    unsigned short* __restrict__ hw16,
    float* __restrict__ asrc, float* __restrict__ adst, int n_nodes)
{
    __shared__ float ws[128 * 64];
#pragma unroll
    for (int i = 0; i < 8; ++i)
        ((float4*)ws)[i * 256 + threadIdx.x] = ((const float4*)Ww)[i * 256 + threadIdx.x];
    __syncthreads();

    const int lane = threadIdx.x & 63;
    const int wid  = threadIdx.x >> 6;
    const int cg   = lane & 15;     // cols 4cg .. 4cg+3
    const int rsub = lane >> 4;     // 0..3
    const int head = cg >> 2;
    const int row0 = (blockIdx.x * 4 + wid) * 16 + rsub * 4;
    if (row0 >= n_nodes) return;

    float acc[4][4];
#pragma unroll
    for (int r = 0; r < 4; ++r)
#pragma unroll
        for (int c = 0; c < 4; ++c) acc[r][c] = 0.f;

    const float* hrow = h + (size_t)row0 * 128;

    for (int k = 0; k < 128; k += 4) {
        float ha[4][4];
#pragma unroll
        for (int r = 0; r < 4; ++r)
            *(float4*)ha[r] = *(const float4*)(hrow + r * 128 + k);
#pragma unroll
        for (int kk = 0; kk < 4; ++kk) {
            float4 w4 = *(const float4*)(&ws[(k + kk) * 64 + cg * 4]);
#pragma unroll
            for (int r = 0; r < 4; ++r) {
                acc[r][0] = __fmaf_rn(ha[r][kk], w4.x, acc[r][0]);
                acc[r][1] = __fmaf_rn(ha[r][kk], w4.y, acc[r][1]);
                acc[r][2] = __fmaf_rn(ha[r][kk], w4.z, acc[r][2]);
                acc[r][3] = __fmaf_rn(ha[r][kk], w4.w, acc[r][3]);
            }
        }
    }
    const float4 b4 = *(const float4*)(bw + cg * 4);
    const int j0 = (cg & 3) * 4;                   // within-head col offset
    const float4 waS = *(const float4*)(Wa + j0);
    const float4 waD = *(const float4*)(Wa + 16 + j0);
    const float ba = *ba_p;
#pragma unroll
    for (int r = 0; r < 4; ++r) {
        float4 o;
        o.x = acc[r][0] + b4.x;
        o.y = acc[r][1] + b4.y;
        o.z = acc[r][2] + b4.z;
        o.w = acc[r][3] + b4.w;
        const size_t idx = (size_t)(row0 + r) * 64 + cg * 4;
        uint2 p;
        p.x = pack_bf16x2(o.x, o.y);
        p.y = pack_bf16x2(o.z, o.w);
        *(uint2*)(hw16 + idx) = p;

        float pas = o.x * waS.x + o.y * waS.y + o.z * waS.z + o.w * waS.w;
        float pad = o.x * waD.x + o.y * waD.y + o.z * waD.z + o.w * waD.w;
        pas += __shfl_xor(pas, 1);
        pas += __shfl_xor(pas, 2);
        pad += __shfl_xor(pad, 1);
        pad += __shfl_xor(pad, 2);
        if ((cg & 3) == 0) {
            asrc[(row0 + r) * 4 + head] = pas;
            adst[(row0 + r) * 4 + head] = pad + ba;
        }
    }
}

// One block per bin: group bin's edges by dst (LDS counting sort), emit CSR.
__global__ __launch_bounds__(256) void k_bincsr(
    const int* __restrict__ bin_cnt, unsigned* __restrict__ binned,
    int* __restrict__ row_start, int* __restrict__ row_cnt, int n_nodes)
{
    __shared__ unsigned data[CAP];
    __shared__ int hist[BINW], lstart[BINW], cursor[BINW];
    const int t = threadIdx.x;
    const int b = blockIdx.x;
    const int cnt = min(bin_cnt[b * 16], CAP);
    const int base = b * CAP;

    if (t < BINW) hist[t] = 0;
    __syncthreads();
    for (int i = t; i < cnt; i += 256) {
        unsigned w = binned[base + i];
        data[i] = w;
        atomicAdd(&hist[w & 127], 1);
    }
    __syncthreads();
    if (t < 64) {
        int carry = 0;
#pragma unroll
        for (int half = 0; half < 2; ++half) {
            int i = half * 64 + t;
            int v = hist[i];
            int x = v;
#pragma unroll
            for (int off = 1; off < 64; off <<= 1) {
                int n_ = __shfl_up(x, off);
                if (t >= off) x += n_;
            }
            lstart[i] = carry + x - v;
            cursor[i] = carry + x - v;
            carry += __shfl(x, 63);
        }
    }
    __syncthreads();
    for (int i = t; i < cnt; i += 256) {
        unsigned w = data[i];
        int pos = atomicAdd(&cursor[w & 127], 1);
        binned[base + pos] = w;
    }
    const int d0 = b * BINW;
    if (t < BINW && d0 + t < n_nodes) {
        row_start[d0 + t] = base + lstart[t];
        row_cnt[d0 + t] = hist[t];
    }
}

// One wave per dst node; lane = output col. Head-dedup exp via shfl; hw in bf16.
__global__ __launch_bounds__(256) void k_gather(
    const unsigned* __restrict__ binned, const int* __restrict__ row_start,
    const int* __restrict__ row_cnt,
    const float* __restrict__ asrc, const float* __restrict__ adst,
    const unsigned short* __restrict__ hw16, float* __restrict__ out, int n_nodes)
{
    int d = blockIdx.x * 4 + (threadIdx.x >> 6);
    if (d >= n_nodes) return;
    const int lane = threadIdx.x & 63;
    const int head = lane >> 4;
    const int eloc = lane & 7;
    const int start = row_start[d];
    const int cnt = row_cnt[d];
    if (cnt <= 0) {
        out[(size_t)d * 64 + lane] = 0.f;
        return;
    }
    const int end = start + cnt;
    const float ad = adst[(unsigned)(d * 4 + head)];
    float acc = 0.f, den = 0.f;

    for (int i = start; i < end; i += 8) {
        int myi = i + eloc;
        int ld = (myi < end) ? myi : start;
        unsigned w = binned[(unsigned)ld];
        int s_p = (int)(w >> 7);
        float a = asrc[(unsigned)(s_p * 4 + head)] + ad;
        a = fmaxf(a, 0.01f * a);
        float ea = __expf(a);
        ea = (myi < end) ? ea : 0.f;
#pragma unroll
        for (int k = 0; k < 8; ++k) {
            int   s_k  = __shfl(s_p, k);
            float ea_k = __shfl(ea, k | (head << 4));
            den += ea_k;
            float hv = __uint_as_float((unsigned)hw16[(unsigned)(s_k * 64 + lane)] << 16);
            acc = __fmaf_rn(ea_k, hv, acc);
        }
    }
    out[(size_t)d * 64 + lane] = acc / den;
}

extern "C" void kernel_launch(void* const* d_in, const int* in_sizes, int n_in,
                              void* d_out, int out_size, void* d_ws, size_t ws_size,
                              hipStream_t stream)
{
    const float* h  = (const float*)d_in[0];
    const float* Ww = (const float*)d_in[1];
    const float* bw = (const float*)d_in[2];
    const float* Wa = (const float*)d_in[3];
    const float* ba = (const float*)d_in[4];
    const int* src  = (const int*)d_in[5];
    const int* dst  = (const int*)d_in[6];

    const int n_nodes = in_sizes[0] / 128;
    const int n_edges = in_sizes[5];
    const int nbins = (n_nodes + BINW - 1) / BINW;   // 391

    // Workspace (4B words):
    // hw16[N*64] bf16 | asrc[N*4] | adst[N*4] | row_start[N] | row_cnt[N] |
    // bin_cnt[nbins*16] | binned[nbins*CAP]
    unsigned short* hw16 = (unsigned short*)d_ws;
    float* asrc          = (float*)(hw16 + (size_t)n_nodes * 64);
    float* adst          = asrc + (size_t)n_nodes * 4;
    int* row_start       = (int*)(adst + (size_t)n_nodes * 4);
    int* row_cnt         = row_start + n_nodes;
    int* bin_cnt         = row_cnt + n_nodes;
    unsigned* binned     = (unsigned*)(bin_cnt + (size_t)nbins * 16);

    float* out = (float*)d_out;

    hipMemsetAsync(bin_cnt, 0, (size_t)nbins * 16 * sizeof(int), stream);

    const int bin_blocks = (n_edges + EPB - 1) / EPB;       // 391
    k_bin<<<bin_blocks, 256, 0, stream>>>(src, dst, bin_cnt, binned, n_edges, nbins);

    const int proj_blocks = (n_nodes + 63) / 64;            // 782
    k_proj<<<proj_blocks, 256, 0, stream>>>(h, Ww, bw, Wa, ba, hw16, asrc, adst, n_nodes);

    k_bincsr<<<nbins, 256, 0, stream>>>(bin_cnt, binned, row_start, row_cnt, n_nodes);

    k_gather<<<(n_nodes + 3) / 4, 256, 0, stream>>>(
        binned, row_start, row_cnt, asrc, adst, hw16, out, n_nodes);
}